// Round 1
// baseline (176.899 us; speedup 1.0000x reference)
//
#include <hip/hip_runtime.h>
#include <hip/hip_cooperative_groups.h>
#include <math.h>

namespace cg = cooperative_groups;

// B=16,H=14,W=14,D=512, L=32, HID=512, A=512. fp32 in/out; bf16 inside MFMA GEMMs.
// R13: single cooperative kernel, 3 phases separated by grid.sync().
// Rationale: total work ~1 GFLOP / ~13 MB unique traffic -> roofline ~2 us, but we
// measure 104.5 us: launch-node overhead (~7-9 us/node) + full drain at each kernel
// boundary dominates. All phases keep grid=256, block=256; 1 block/CU co-resident
// so grid sync is legal. Phase bodies are verbatim from the verified R12 kernels.

typedef __attribute__((ext_vector_type(8))) short short8;
typedef __attribute__((ext_vector_type(4))) float f32x4;

__device__ __forceinline__ unsigned f2bf_u(float x) {
    union { float f; unsigned u; } c; c.f = x;
    return (c.u + 0x7FFFu + ((c.u >> 16) & 1u)) >> 16;   // RNE, finite inputs
}
__device__ __forceinline__ unsigned pack2(float lo, float hi) {
    return f2bf_u(lo) | (f2bf_u(hi) << 16);
}
__device__ __forceinline__ uint4 pack8(const float4 a, const float4 b) {
    uint4 r;
    r.x = pack2(a.x, a.y); r.y = pack2(a.z, a.w);
    r.z = pack2(b.x, b.y); r.w = pack2(b.z, b.w);
    return r;
}

// LDS arena: max(gemm 64 KB, mid 67456 B)
#define SMEM_BYTES 67456

// ---- GEMM phase: C = A(512,512)_f32 . B(512,512)_f32^T + bias[n] [* hmul] ----
// tile (m0=(bid>>4)*32, n0=(bid&15)*32); 4 waves split K + LDS reduce.
template<int HMUL>
__device__ void gemm_body(char* smem,
    const float* __restrict__ Af, const float* __restrict__ Bf,
    const float* __restrict__ bias, const float* __restrict__ hmul,
    float* __restrict__ C)
{
    uint4* As = (uint4*)smem;               // 2048 slots (32KB)
    uint4* Bs = (uint4*)(smem + 32768);     // 2048 slots (32KB)
    float* red = (float*)smem;              // overlays As after sync (16KB)
    const int tid = threadIdx.x, bid = blockIdx.x;

    const int m0 = (bid >> 4) * 32, n0 = (bid & 15) * 32;
    #pragma unroll
    for (int j = 0; j < 8; ++j) {
        const int S = tid + 256 * j;
        const int i = S >> 6, ln = S & 63;
        const int t = i & 1, s = i >> 1;
        const int row  = t * 16 + (ln & 15);
        const int col8 = s * 4 + (ln >> 4);
        const float* ap = Af + (size_t)(m0 + row) * 512 + col8 * 8;
        const float* bp = Bf + (size_t)(n0 + row) * 512 + col8 * 8;
        As[S] = pack8(*(const float4*)ap, *(const float4*)(ap + 4));
        Bs[S] = pack8(*(const float4*)bp, *(const float4*)(bp + 4));
    }
    __syncthreads();

    const int w = tid >> 6, ln = tid & 63;
    f32x4 acc[4];                            // fo = tm*2+tn
    #pragma unroll
    for (int fo = 0; fo < 4; ++fo) acc[fo] = (f32x4){0.f,0.f,0.f,0.f};
    #pragma unroll
    for (int sl = 0; sl < 4; ++sl) {
        const int s = 4 * w + sl;
        const short8 a0 = *(const short8*)&As[(2*s+0)*64 + ln];
        const short8 a1 = *(const short8*)&As[(2*s+1)*64 + ln];
        const short8 b0 = *(const short8*)&Bs[(2*s+0)*64 + ln];
        const short8 b1 = *(const short8*)&Bs[(2*s+1)*64 + ln];
        acc[0] = __builtin_amdgcn_mfma_f32_16x16x32_bf16(a0, b0, acc[0], 0, 0, 0);
        acc[1] = __builtin_amdgcn_mfma_f32_16x16x32_bf16(a0, b1, acc[1], 0, 0, 0);
        acc[2] = __builtin_amdgcn_mfma_f32_16x16x32_bf16(a1, b0, acc[2], 0, 0, 0);
        acc[3] = __builtin_amdgcn_mfma_f32_16x16x32_bf16(a1, b1, acc[3], 0, 0, 0);
    }
    __syncthreads();                         // done reading As/Bs
    #pragma unroll
    for (int fo = 0; fo < 4; ++fo)
        #pragma unroll
        for (int r = 0; r < 4; ++r)
            red[w*1024 + fo*256 + r*64 + ln] = acc[fo][r];
    __syncthreads();
    #pragma unroll
    for (int j = 0; j < 4; ++j) {
        const int o = tid + 256 * j;
        float v = red[o] + red[1024 + o] + red[2048 + o] + red[3072 + o];
        const int fo = o >> 8, r = (o >> 6) & 3, l2 = o & 63;
        // C/D layout: col = lane&15, row = (lane>>4)*4 + reg [m89-verified]
        const int m = m0 + (fo >> 1) * 16 + ((l2 >> 4) << 2) + r;
        const int n = n0 + (fo & 1) * 16 + (l2 & 15);
        v += bias[n];
        if (HMUL) v *= hmul[(size_t)m * 512 + n];
        C[(size_t)m * 512 + n] = v;
    }
}

// ---- mid phase: block (b = bx>>4, s = bx&15) owns l0 = 2s, l0+1 ----
// scores (196x2) -> softmax -> attn(out, fp32) -> ctx rows (fp32 -> ws)
__device__ void mid_body(char* smem,
    const float* __restrict__ maps, const float* __restrict__ hlin,
    const float* __restrict__ W_rect, const float* __restrict__ b_rect,
    float* __restrict__ attn_out, float* __restrict__ ctx_out)
{
    const int b = blockIdx.x >> 4, s = blockIdx.x & 15;
    const int l0 = 2 * s;
    const int tid = threadIdx.x;
    const int pi = tid >> 4, k = tid & 15;

    float* h0    = (float*)smem;             // 512 f
    float* h1    = h0 + 512;                 // 512 f
    float* wv    = h1 + 512;                 // 512 f
    float* ftile = wv + 512;                 // 16*516 f
    float* red0  = ftile + 16 * 516;         // 208*16 f
    float* red1  = red0 + 208 * 16;          // 208*16 f
    float* smrow = red1 + 208 * 16;          // 2*208 f  (total 67456 B)

    // stage hlin rows l0,l0+1 and W_rect
    {
        const float4* H0 = (const float4*)(hlin + ((size_t)b * 32 + l0) * 512);
        const float4* H1 = (const float4*)(hlin + ((size_t)b * 32 + l0 + 1) * 512);
        const float4* WV = (const float4*)W_rect;
        if (tid < 128) { ((float4*)h0)[tid] = H0[tid]; ((float4*)wv)[tid] = WV[tid]; }
        else           { ((float4*)h1)[tid - 128] = H1[tid - 128]; }
    }
    __syncthreads();

    // hoist this thread's a-set (32 elems, bank-rotated) into registers
    int aoff[8];
    float4 h0r[8], h1r[8], wr[8];
    #pragma unroll
    for (int j = 0; j < 8; ++j) {
        aoff[j] = k * 32 + ((j + k) & 7) * 4;
        h0r[j] = *(const float4*)&h0[aoff[j]];
        h1r[j] = *(const float4*)&h1[aoff[j]];
        wr[j]  = *(const float4*)&wv[aoff[j]];
    }

    const float* mb = maps + (size_t)b * 196 * 512;

    // scores: 13 chunks of 16 p-rows through LDS
    for (int c = 0; c < 13; ++c) {
        __syncthreads();
        #pragma unroll
        for (int it = 0; it < 8; ++it) {
            const int idx = tid + 256 * it;      // 0..2047 float4
            const int r = idx >> 7, c4 = idx & 127;
            int p = c * 16 + r; if (p > 195) p = 195;
            *(float4*)&ftile[r * 516 + c4 * 4] = *(const float4*)(mb + (size_t)p * 512 + c4 * 4);
        }
        __syncthreads();
        float s0 = 0.f, s1 = 0.f;
        #pragma unroll
        for (int j = 0; j < 8; ++j) {
            const float4 f = *(const float4*)&ftile[pi * 516 + aoff[j]];
            const float4 A = h0r[j], Bv = h1r[j], W = wr[j];
            s0 += fmaxf(f.x + A.x, 0.f) * W.x + fmaxf(f.y + A.y, 0.f) * W.y
                + fmaxf(f.z + A.z, 0.f) * W.z + fmaxf(f.w + A.w, 0.f) * W.w;
            s1 += fmaxf(f.x + Bv.x, 0.f) * W.x + fmaxf(f.y + Bv.y, 0.f) * W.y
                + fmaxf(f.z + Bv.z, 0.f) * W.z + fmaxf(f.w + Bv.w, 0.f) * W.w;
        }
        const int p = c * 16 + pi;
        red0[p * 16 + k] = s0;
        red1[p * 16 + k] = s1;
    }
    __syncthreads();

    // finalize raw scores into smrow[l][p]
    const float br = b_rect[0];
    for (int idx = tid; idx < 392; idx += 256) {
        const int l = idx & 1, p = idx >> 1;
        const float* rb = (l ? red1 : red0) + p * 16;
        const float4 a = *(const float4*)rb,      bq = *(const float4*)(rb + 4);
        const float4 cq = *(const float4*)(rb + 8), dq = *(const float4*)(rb + 12);
        smrow[l * 208 + p] = (a.x + a.y + a.z + a.w) + (bq.x + bq.y + bq.z + bq.w)
                           + (cq.x + cq.y + cq.z + cq.w) + (dq.x + dq.y + dq.z + dq.w) + br;
    }
    __syncthreads();

    // softmax: wave 0 -> l0, wave 1 -> l0+1
    const int wave = tid >> 6, lane = tid & 63;
    if (wave < 2) {
        float v[4];
        #pragma unroll
        for (int i = 0; i < 4; ++i) {
            const int p = lane + 64 * i;
            v[i] = (p < 196) ? smrow[wave * 208 + p] : -INFINITY;
        }
        float m = fmaxf(fmaxf(v[0], v[1]), fmaxf(v[2], v[3]));
        for (int off = 32; off > 0; off >>= 1) m = fmaxf(m, __shfl_down(m, off));
        m = __shfl(m, 0);
        float e[4], ssum = 0.f;
        #pragma unroll
        for (int i = 0; i < 4; ++i) {
            const int p = lane + 64 * i;
            e[i] = (p < 196) ? __expf(v[i] - m) : 0.f;
            ssum += e[i];
        }
        for (int off = 32; off > 0; off >>= 1) ssum += __shfl_down(ssum, off);
        ssum = __shfl(ssum, 0);
        const float inv = 1.f / ssum;
        float* ao = attn_out + ((size_t)b * 32 + l0 + wave) * 196;
        #pragma unroll
        for (int i = 0; i < 4; ++i) {
            const int p = lane + 64 * i;
            if (p < 196) {
                const float at = e[i] * inv;
                smrow[wave * 208 + p] = at;
                ao[p] = at;
            }
        }
    }
    __syncthreads();

    // ctx pass: thread owns d0 = 2*tid; coalesced f2 stream over maps
    const int d0 = tid * 2;
    float a0 = 0.f, a1 = 0.f, c0 = 0.f, c1 = 0.f;
    for (int p = 0; p < 196; ++p) {
        const float2 f = *(const float2*)(mb + (size_t)p * 512 + d0);
        const float w0 = smrow[p], w1 = smrow[208 + p];
        a0 += w0 * f.x; a1 += w0 * f.y;
        c0 += w1 * f.x; c1 += w1 * f.y;
    }
    float2 o0; o0.x = a0; o0.y = a1;
    float2 o1; o1.x = c0; o1.y = c1;
    *(float2*)(ctx_out + ((size_t)b * 32 + l0) * 512 + d0)     = o0;
    *(float2*)(ctx_out + ((size_t)b * 32 + l0 + 1) * 512 + d0) = o1;
}

// ---- single cooperative kernel: gemm1 -> sync -> mid -> sync -> gemm2 ----
__global__ __launch_bounds__(256) void fused_kernel(
    const float* __restrict__ maps, const float* __restrict__ hiddens,
    const float* __restrict__ W_hidden, const float* __restrict__ b_hidden,
    const float* __restrict__ W_rect, const float* __restrict__ b_rect,
    const float* __restrict__ W_co, const float* __restrict__ b_co,
    float* __restrict__ out_co, float* __restrict__ attn_out,
    float* __restrict__ hlin_ws, float* __restrict__ ctx_ws)
{
    __shared__ __align__(16) char smem[SMEM_BYTES];
    cg::grid_group grid = cg::this_grid();

    // 1) hlin = hiddens @ W_hidden^T + b_hidden -> ws
    gemm_body<0>(smem, hiddens, W_hidden, b_hidden, (const float*)nullptr, hlin_ws);
    grid.sync();
    // 2) scores + softmax (-> attn_out) + ctx (fp32 -> ws)
    mid_body(smem, maps, hlin_ws, W_rect, b_rect, attn_out, ctx_ws);
    grid.sync();
    // 3) out_co = (ctx @ W_co^T + b_co) * hiddens
    gemm_body<1>(smem, ctx_ws, W_co, b_co, hiddens, out_co);
}

extern "C" void kernel_launch(void* const* d_in, const int* in_sizes, int n_in,
                              void* d_out, int out_size, void* d_ws, size_t ws_size,
                              hipStream_t stream)
{
    const float* maps     = (const float*)d_in[0];
    const float* hiddens  = (const float*)d_in[1];
    const float* W_hidden = (const float*)d_in[2];
    const float* b_hidden = (const float*)d_in[3];
    const float* W_rect   = (const float*)d_in[4];
    const float* b_rect   = (const float*)d_in[5];
    const float* W_co     = (const float*)d_in[6];
    const float* b_co     = (const float*)d_in[7];

    float* out_co   = (float*)d_out;                    // (512,512) final
    float* out_attn = out_co + (size_t)512 * 512;       // (512,196)
    float* hlin     = (float*)d_ws;                     // (512,512) fp32
    float* ctx      = hlin + (size_t)512 * 512;         // (512,512) fp32

    void* kargs[12] = {
        (void*)&maps, (void*)&hiddens, (void*)&W_hidden, (void*)&b_hidden,
        (void*)&W_rect, (void*)&b_rect, (void*)&W_co, (void*)&b_co,
        (void*)&out_co, (void*)&out_attn, (void*)&hlin, (void*)&ctx
    };
    hipLaunchCooperativeKernel((void*)fused_kernel, dim3(256), dim3(256),
                               kargs, 0, stream);
}

// Round 2
// 151.086 us; speedup vs baseline: 1.1709x; 1.1709x over previous
//
#include <hip/hip_runtime.h>
#include <math.h>

// B=16,H=14,W=14,D=512, L=32, HID=512, A=512. fp32 throughout.
// R14: ONE regular (graph-capturable) kernel, fully block-local — no grid sync,
// no cooperative launch (R13 showed coop launch costs ~90 us/iter: not captured).
// Block bx -> (xcd = bx&7, idx = bx>>3): b = 2*xcd + (idx&1), l0 = 2*(idx>>3... )
//   b = 2*xcd+(idx&1), s = idx>>1, l0 = 2*s.
// XCD-aware mapping keeps maps[b] (802 KB per XCD) resident in the 4 MB per-XCD
// L2, so maps is HBM-fetched once total (R13: 51 MB re-fetch across XCDs).
// Phases (all in-block, hlin/ctx live in LDS only):
//   A: hlin[2][512] = hiddens[b,l0:l0+2] @ W_hidden^T + b_hidden   (fp32 VALU)
//   B: scores -> softmax -> attn_out + ctx[2][512] (verbatim R12 mid machinery)
//   C: out[2][512] = (ctx @ W_co^T + b_co) * hiddens[2 rows]       (fp32 VALU)
// W duplication cost: 32 blocks/XCD x 1 MB/phase = 32 MB/XCD through L2 (~7 us)
// per GEMM phase — cheaper than the 2 kernel nodes + drains it replaces.

__global__ __launch_bounds__(256) void coatt_kernel(
    const float* __restrict__ maps, const float* __restrict__ hiddens,
    const float* __restrict__ W_hidden, const float* __restrict__ b_hidden,
    const float* __restrict__ W_rect, const float* __restrict__ b_rect,
    const float* __restrict__ W_co, const float* __restrict__ b_co,
    float* __restrict__ out_co, float* __restrict__ attn_out)
{
    // ---- LDS arena (17888 floats = 71552 B) ----
    __shared__ __align__(16) float arena[17888];
    float* hidA  = arena;              // 512   hiddens row l0
    float* hidB  = arena + 512;        // 512   hiddens row l0+1
    float* wv    = arena + 1024;       // 512   W_rect
    float* h0    = arena + 1536;       // 512   hlin row l0
    float* h1    = arena + 2048;       // 512   hlin row l0+1
    float* ftile = arena + 2560;       // 16*516
    float* red0  = arena + 10816;      // 208*16  (ctx0/ctx1 overlay after scores)
    float* red1  = arena + 14144;      // 208*16
    float* smrow = arena + 17472;      // 2*208
    float* ctx0  = red0;               // 512 (overlay, used after softmax)
    float* ctx1  = red0 + 512;         // 512

    const int tid = threadIdx.x, bx = blockIdx.x;
    const int xcd = bx & 7, idx = bx >> 3;
    const int b  = (xcd << 1) | (idx & 1);
    const int l0 = (idx >> 1) * 2;

    // ---- stage hiddens rows + W_rect ----
    {
        const float4* HA = (const float4*)(hiddens + ((size_t)b * 32 + l0) * 512);
        const float4* HB = (const float4*)(hiddens + ((size_t)b * 32 + l0 + 1) * 512);
        const float4* WV = (const float4*)W_rect;
        if (tid < 128) { ((float4*)hidA)[tid] = HA[tid]; ((float4*)wv)[tid] = WV[tid]; }
        else           { ((float4*)hidB)[tid - 128] = HB[tid - 128]; }
    }
    __syncthreads();

    // ---- Phase A: hlin rows (thread owns cols n=tid and n=tid+256) ----
    {
        const int n0 = tid, n1 = tid + 256;
        const float4* wr0 = (const float4*)(W_hidden + (size_t)n0 * 512);
        const float4* wr1 = (const float4*)(W_hidden + (size_t)n1 * 512);
        const float4* a4 = (const float4*)hidA;
        const float4* b4 = (const float4*)hidB;
        float s00 = 0.f, s01 = 0.f, s10 = 0.f, s11 = 0.f;
        #pragma unroll 8
        for (int j = 0; j < 128; ++j) {
            const float4 w0 = wr0[j], w1 = wr1[j];
            const float4 ha = a4[j], hb = b4[j];           // LDS broadcast
            s00 += w0.x*ha.x + w0.y*ha.y + w0.z*ha.z + w0.w*ha.w;
            s01 += w0.x*hb.x + w0.y*hb.y + w0.z*hb.z + w0.w*hb.w;
            s10 += w1.x*ha.x + w1.y*ha.y + w1.z*ha.z + w1.w*ha.w;
            s11 += w1.x*hb.x + w1.y*hb.y + w1.z*hb.z + w1.w*hb.w;
        }
        const float bi0 = b_hidden[n0], bi1 = b_hidden[n1];
        h0[n0] = s00 + bi0;  h1[n0] = s01 + bi0;
        h0[n1] = s10 + bi1;  h1[n1] = s11 + bi1;
    }
    __syncthreads();

    // ---- Phase B: scores -> softmax -> attn + ctx (R12 mid machinery) ----
    const int pi = tid >> 4, k = tid & 15;

    // hoist this thread's a-set (32 elems, bank-rotated) into registers
    int aoff[8];
    float4 h0r[8], h1r[8], wr[8];
    #pragma unroll
    for (int j = 0; j < 8; ++j) {
        aoff[j] = k * 32 + ((j + k) & 7) * 4;
        h0r[j] = *(const float4*)&h0[aoff[j]];
        h1r[j] = *(const float4*)&h1[aoff[j]];
        wr[j]  = *(const float4*)&wv[aoff[j]];
    }

    const float* mb = maps + (size_t)b * 196 * 512;

    // scores: 13 chunks of 16 p-rows through LDS
    for (int c = 0; c < 13; ++c) {
        __syncthreads();
        #pragma unroll
        for (int it = 0; it < 8; ++it) {
            const int idx2 = tid + 256 * it;     // 0..2047 float4
            const int r = idx2 >> 7, c4 = idx2 & 127;
            int p = c * 16 + r; if (p > 195) p = 195;
            *(float4*)&ftile[r * 516 + c4 * 4] = *(const float4*)(mb + (size_t)p * 512 + c4 * 4);
        }
        __syncthreads();
        float s0 = 0.f, s1 = 0.f;
        #pragma unroll
        for (int j = 0; j < 8; ++j) {
            const float4 f = *(const float4*)&ftile[pi * 516 + aoff[j]];
            const float4 A = h0r[j], Bv = h1r[j], W = wr[j];
            s0 += fmaxf(f.x + A.x, 0.f) * W.x + fmaxf(f.y + A.y, 0.f) * W.y
                + fmaxf(f.z + A.z, 0.f) * W.z + fmaxf(f.w + A.w, 0.f) * W.w;
            s1 += fmaxf(f.x + Bv.x, 0.f) * W.x + fmaxf(f.y + Bv.y, 0.f) * W.y
                + fmaxf(f.z + Bv.z, 0.f) * W.z + fmaxf(f.w + Bv.w, 0.f) * W.w;
        }
        const int p = c * 16 + pi;
        red0[p * 16 + k] = s0;
        red1[p * 16 + k] = s1;
    }
    __syncthreads();

    // finalize raw scores into smrow[l][p]
    const float br = b_rect[0];
    for (int i2 = tid; i2 < 392; i2 += 256) {
        const int l = i2 & 1, p = i2 >> 1;
        const float* rb = (l ? red1 : red0) + p * 16;
        const float4 a = *(const float4*)rb,      bq = *(const float4*)(rb + 4);
        const float4 cq = *(const float4*)(rb + 8), dq = *(const float4*)(rb + 12);
        smrow[l * 208 + p] = (a.x + a.y + a.z + a.w) + (bq.x + bq.y + bq.z + bq.w)
                           + (cq.x + cq.y + cq.z + cq.w) + (dq.x + dq.y + dq.z + dq.w) + br;
    }
    __syncthreads();

    // softmax: wave 0 -> l0, wave 1 -> l0+1
    const int wave = tid >> 6, lane = tid & 63;
    if (wave < 2) {
        float v[4];
        #pragma unroll
        for (int i = 0; i < 4; ++i) {
            const int p = lane + 64 * i;
            v[i] = (p < 196) ? smrow[wave * 208 + p] : -INFINITY;
        }
        float m = fmaxf(fmaxf(v[0], v[1]), fmaxf(v[2], v[3]));
        for (int off = 32; off > 0; off >>= 1) m = fmaxf(m, __shfl_down(m, off));
        m = __shfl(m, 0);
        float e[4], ssum = 0.f;
        #pragma unroll
        for (int i = 0; i < 4; ++i) {
            const int p = lane + 64 * i;
            e[i] = (p < 196) ? __expf(v[i] - m) : 0.f;
            ssum += e[i];
        }
        for (int off = 32; off > 0; off >>= 1) ssum += __shfl_down(ssum, off);
        ssum = __shfl(ssum, 0);
        const float inv = 1.f / ssum;
        float* ao = attn_out + ((size_t)b * 32 + l0 + wave) * 196;
        #pragma unroll
        for (int i = 0; i < 4; ++i) {
            const int p = lane + 64 * i;
            if (p < 196) {
                const float at = e[i] * inv;
                smrow[wave * 208 + p] = at;
                ao[p] = at;
            }
        }
    }
    __syncthreads();

    // ctx pass: thread owns d0 = 2*tid; maps now L2-resident (XCD mapping)
    {
        const int d0 = tid * 2;
        float a0 = 0.f, a1 = 0.f, c0 = 0.f, c1 = 0.f;
        for (int p = 0; p < 196; ++p) {
            const float2 f = *(const float2*)(mb + (size_t)p * 512 + d0);
            const float w0 = smrow[p], w1 = smrow[208 + p];
            a0 += w0 * f.x; a1 += w0 * f.y;
            c0 += w1 * f.x; c1 += w1 * f.y;
        }
        __syncthreads();                 // red0 dead -> safe to overlay ctx0/ctx1
        float2 o0; o0.x = a0; o0.y = a1;
        float2 o1; o1.x = c0; o1.y = c1;
        *(float2*)&ctx0[d0] = o0;
        *(float2*)&ctx1[d0] = o1;
    }
    __syncthreads();

    // ---- Phase C: out rows = (ctx @ W_co^T + b_co) * hiddens ----
    {
        const int n0 = tid, n1 = tid + 256;
        const float4* wr0 = (const float4*)(W_co + (size_t)n0 * 512);
        const float4* wr1 = (const float4*)(W_co + (size_t)n1 * 512);
        const float4* c04 = (const float4*)ctx0;
        const float4* c14 = (const float4*)ctx1;
        float s00 = 0.f, s01 = 0.f, s10 = 0.f, s11 = 0.f;
        #pragma unroll 8
        for (int j = 0; j < 128; ++j) {
            const float4 w0 = wr0[j], w1 = wr1[j];
            const float4 ca = c04[j], cb = c14[j];          // LDS broadcast
            s00 += w0.x*ca.x + w0.y*ca.y + w0.z*ca.z + w0.w*ca.w;
            s01 += w0.x*cb.x + w0.y*cb.y + w0.z*cb.z + w0.w*cb.w;
            s10 += w1.x*ca.x + w1.y*ca.y + w1.z*ca.z + w1.w*ca.w;
            s11 += w1.x*cb.x + w1.y*cb.y + w1.z*cb.z + w1.w*cb.w;
        }
        const float bc0 = b_co[n0], bc1 = b_co[n1];
        float* o0 = out_co + ((size_t)b * 32 + l0) * 512;
        float* o1 = out_co + ((size_t)b * 32 + l0 + 1) * 512;
        o0[n0] = (s00 + bc0) * hidA[n0];
        o1[n0] = (s01 + bc0) * hidB[n0];
        o0[n1] = (s10 + bc1) * hidA[n1];
        o1[n1] = (s11 + bc1) * hidB[n1];
    }
}

extern "C" void kernel_launch(void* const* d_in, const int* in_sizes, int n_in,
                              void* d_out, int out_size, void* d_ws, size_t ws_size,
                              hipStream_t stream)
{
    const float* maps     = (const float*)d_in[0];
    const float* hiddens  = (const float*)d_in[1];
    const float* W_hidden = (const float*)d_in[2];
    const float* b_hidden = (const float*)d_in[3];
    const float* W_rect   = (const float*)d_in[4];
    const float* b_rect   = (const float*)d_in[5];
    const float* W_co     = (const float*)d_in[6];
    const float* b_co     = (const float*)d_in[7];

    float* out_co   = (float*)d_out;                    // (512,512)
    float* out_attn = out_co + (size_t)512 * 512;       // (512,196)

    hipLaunchKernelGGL(coatt_kernel, dim3(256), dim3(256), 0, stream,
                       maps, hiddens, W_hidden, b_hidden, W_rect, b_rect,
                       W_co, b_co, out_co, out_attn);
}